// Round 7
// baseline (5070.651 us; speedup 1.0000x reference)
//
#include <hip/hip_runtime.h>

#define T_N 4096
#define B_N 64
#define I_N 128
#define H_N 128
#define BH  (B_N * H_N)

// ---------------------------------------------------------------------------
// Phase 1: xp = x @ W_ih^T + b_ih -> into out (in-place with phase 2).
// Unchanged from R2-R6.
// ---------------------------------------------------------------------------
__global__ __launch_bounds__(256) void xproj_kernel(
    const float* __restrict__ x, const float* __restrict__ Wih,
    const float* __restrict__ bih, float* __restrict__ xp)
{
    __shared__ float wt[I_N][H_N];   // wt[k][j] = Wih[j][k], 64 KB
    const int tid = threadIdx.x;

    {
        const float4* w4 = (const float4*)Wih;
        #pragma unroll
        for (int it = 0; it < 16; ++it) {
            int i = tid * 16 + it;          // 0..4095 float4s
            float4 v = w4[i];
            int r = i >> 5;                 // W row j
            int k = (i & 31) << 2;          // k base
            wt[k + 0][r] = v.x;
            wt[k + 1][r] = v.y;
            wt[k + 2][r] = v.z;
            wt[k + 3][r] = v.w;
        }
    }
    __syncthreads();

    const int  tx   = tid & 15;
    const int  ty   = tid >> 4;
    const long row0 = (long)blockIdx.x * 128;
    const float* xbase = x + (row0 + ty * 8) * I_N;

    float acc[8][8];
    #pragma unroll
    for (int r = 0; r < 8; ++r)
        #pragma unroll
        for (int c = 0; c < 8; ++c) acc[r][c] = 0.0f;

    #pragma unroll 2
    for (int k4 = 0; k4 < I_N / 4; ++k4) {
        float4 xv[8];
        #pragma unroll
        for (int r = 0; r < 8; ++r)
            xv[r] = *(const float4*)(xbase + r * I_N + k4 * 4);

        #pragma unroll
        for (int kk = 0; kk < 4; ++kk) {
            int k = k4 * 4 + kk;
            float4 w0 = *(const float4*)&wt[k][tx * 4];
            float4 w1 = *(const float4*)&wt[k][64 + tx * 4];
            #pragma unroll
            for (int r = 0; r < 8; ++r) {
                float xk = (kk == 0) ? xv[r].x : (kk == 1) ? xv[r].y
                         : (kk == 2) ? xv[r].z : xv[r].w;
                acc[r][0] = fmaf(xk, w0.x, acc[r][0]);
                acc[r][1] = fmaf(xk, w0.y, acc[r][1]);
                acc[r][2] = fmaf(xk, w0.z, acc[r][2]);
                acc[r][3] = fmaf(xk, w0.w, acc[r][3]);
                acc[r][4] = fmaf(xk, w1.x, acc[r][4]);
                acc[r][5] = fmaf(xk, w1.y, acc[r][5]);
                acc[r][6] = fmaf(xk, w1.z, acc[r][6]);
                acc[r][7] = fmaf(xk, w1.w, acc[r][7]);
            }
        }
    }

    float4 b0 = *(const float4*)(bih + tx * 4);
    float4 b1 = *(const float4*)(bih + 64 + tx * 4);
    #pragma unroll
    for (int r = 0; r < 8; ++r) {
        long row = row0 + ty * 8 + r;
        float4 o0, o1;
        o0.x = acc[r][0] + b0.x;  o0.y = acc[r][1] + b0.y;
        o0.z = acc[r][2] + b0.z;  o0.w = acc[r][3] + b0.w;
        o1.x = acc[r][4] + b1.x;  o1.y = acc[r][5] + b1.y;
        o1.z = acc[r][6] + b1.z;  o1.w = acc[r][7] + b1.w;
        *(float4*)(xp + row * H_N + tx * 4)      = o0;
        *(float4*)(xp + row * H_N + 64 + tx * 4) = o1;
    }
}

// ---------------------------------------------------------------------------
// Phase 2: scan — EXACTLY the R6 kernel (512 thr, p=lane&15, jg 4/wave,
// DPP row_ror reduce, hbuf[2][16][12], raw s_barrier + lgkmcnt(0)).
// ---------------------------------------------------------------------------
__device__ __forceinline__ float tanh_pade(float x) {
    float u = x * x;
    float n = fmaf(u, u + 105.0f, 945.0f);
    float d = fmaf(u, fmaf(15.0f, u, 420.0f), 945.0f);
    float t = x * n * __builtin_amdgcn_rcpf(d);
    return fminf(1.0f, fmaxf(-1.0f, t));
}

#define ROR1 0x121
#define ROR2 0x122
#define ROR4 0x124
#define ROR8 0x128

__device__ __forceinline__ float ror_add(float v, const int ctrl) {
    int s = __float_as_int(v);
    int r;
    switch (ctrl) {
        case ROR1: r = __builtin_amdgcn_update_dpp(0, s, ROR1, 0xF, 0xF, true); break;
        case ROR2: r = __builtin_amdgcn_update_dpp(0, s, ROR2, 0xF, 0xF, true); break;
        case ROR4: r = __builtin_amdgcn_update_dpp(0, s, ROR4, 0xF, 0xF, true); break;
        default:   r = __builtin_amdgcn_update_dpp(0, s, ROR8, 0xF, 0xF, true); break;
    }
    return v + __int_as_float(r);
}

#define DOT4(W4, H4)                                                          \
    fmaf((W4).x, (H4).x, fmaf((W4).y, (H4).y,                                 \
    fmaf((W4).z, (H4).z, (W4).w * (H4).w)))

__global__ __launch_bounds__(512, 1) void scan_kernel(
    const float* __restrict__ Whh, const float* __restrict__ bhh,
    const float* __restrict__ h0, float* __restrict__ out)
{
    const int tid  = threadIdx.x;
    const int b    = blockIdx.x;
    const int lane = tid & 63;
    const int wv   = tid >> 6;
    const int p    = lane & 15;
    const int jg   = (lane >> 4) + 4 * wv;
    __shared__ float hbuf[2][16][12];

    float4 w4[4][2];
    #pragma unroll
    for (int j = 0; j < 4; ++j)
        #pragma unroll
        for (int c = 0; c < 2; ++c)
            w4[j][c] = *(const float4*)(Whh + (4 * jg + j) * H_N + 8 * p + 4 * c);

    const float4 bh4 = *(const float4*)(bhh + 4 * jg);

    if (tid < H_N) hbuf[0][tid >> 3][tid & 7] = h0[b * H_N + tid];

    const float* xq = out + b * H_N + 4 * jg;
    float*       oq = out + b * H_N + 4 * jg;

    float4 xv[4];
    #pragma unroll
    for (int d = 0; d < 4; ++d)
        xv[d] = *(const float4*)(xq + (size_t)d * BH);

    __syncthreads();

#define RNN_STEP(T0, D, CUR) do {                                             \
        float4 hv0 = *(const float4*)&hbuf[CUR][p][0];                        \
        float4 hv1 = *(const float4*)&hbuf[CUR][p][4];                        \
        float s0 = DOT4(w4[0][0], hv0) + DOT4(w4[0][1], hv1);                 \
        float s1 = DOT4(w4[1][0], hv0) + DOT4(w4[1][1], hv1);                 \
        float s2 = DOT4(w4[2][0], hv0) + DOT4(w4[2][1], hv1);                 \
        float s3 = DOT4(w4[3][0], hv0) + DOT4(w4[3][1], hv1);                 \
        s0 = ror_add(s0, ROR1); s1 = ror_add(s1, ROR1);                       \
        s2 = ror_add(s2, ROR1); s3 = ror_add(s3, ROR1);                       \
        s0 = ror_add(s0, ROR2); s1 = ror_add(s1, ROR2);                       \
        s2 = ror_add(s2, ROR2); s3 = ror_add(s3, ROR2);                       \
        s0 = ror_add(s0, ROR4); s1 = ror_add(s1, ROR4);                       \
        s2 = ror_add(s2, ROR4); s3 = ror_add(s3, ROR4);                       \
        s0 = ror_add(s0, ROR8); s1 = ror_add(s1, ROR8);                       \
        s2 = ror_add(s2, ROR8); s3 = ror_add(s3, ROR8);                       \
        float4 h4;                                                            \
        h4.x = tanh_pade(s0 + xv[D].x + bh4.x);                               \
        h4.y = tanh_pade(s1 + xv[D].y + bh4.y);                               \
        h4.z = tanh_pade(s2 + xv[D].z + bh4.z);                               \
        h4.w = tanh_pade(s3 + xv[D].w + bh4.w);                               \
        if (p == 0)                                                           \
            *(float4*)&hbuf[(CUR) ^ 1][jg >> 1][(jg & 1) << 2] = h4;          \
        if ((T0) + 4 < T_N)                                                   \
            xv[D] = *(const float4*)(xq + (size_t)((T0) + 4) * BH);           \
        if (p == 0) {                                                         \
            *(float4*)(oq + (size_t)(T0) * BH) = h4;                          \
            if ((T0) == T_N - 1) *(float4*)(oq + (size_t)T_N * BH) = h4;      \
        }                                                                     \
        asm volatile("s_waitcnt lgkmcnt(0)" ::: "memory");                    \
        __builtin_amdgcn_s_barrier();                                         \
        asm volatile("" ::: "memory");                                        \
    } while (0)

    for (int t = 0; t < T_N; t += 4) {
        RNN_STEP(t + 0, 0, 0);
        RNN_STEP(t + 1, 1, 1);
        RNN_STEP(t + 2, 2, 0);
        RNN_STEP(t + 3, 3, 1);
    }
#undef RNN_STEP
}

// ---------------------------------------------------------------------------
// PROBES (write only to d_ws; real output untouched). Decompose the
// ~1100cyc/step floor: P0 clock, P1 barrier, P2 +LDS handoff, P3 full-VALU
// no-global. scan - P3 = global store/prefetch path.
// ---------------------------------------------------------------------------

// P0: 64 dependent FMAs per iter -> latency-bound at ANY clock.
// Expected 4096*64*4cyc = 1.05 Mcyc = 437 us @ 2.4 GHz. Slower => downclock.
__global__ __launch_bounds__(512, 1) void probe_clock(float* ws) {
    float a = 1.0f + (float)threadIdx.x * 1e-7f;
    const float b = 0.99990f, c = 1e-9f;
    for (int t = 0; t < T_N; ++t) {
        #pragma unroll
        for (int i = 0; i < 64; ++i) a = fmaf(a, b, c);
    }
    if (threadIdx.x == 0) ws[blockIdx.x] = a;
}

// P1: bare barrier loop (8 waves, 1 block/CU) = barrier machinery floor.
__global__ __launch_bounds__(512, 1) void probe_barrier(float* ws) {
    float a = (float)threadIdx.x;
    for (int t = 0; t < T_N; ++t) {
        __builtin_amdgcn_s_barrier();
        a += 1.0f;
    }
    if (threadIdx.x == 0) ws[64 + blockIdx.x] = a;
}

// P2: barrier + the exact LDS read/write/lgkm handoff of the scan (no math).
__global__ __launch_bounds__(512, 1) void probe_lds(float* ws) {
    const int tid = threadIdx.x, lane = tid & 63, wv = tid >> 6;
    const int p = lane & 15, jg = (lane >> 4) + 4 * wv;
    __shared__ float hbuf[2][16][12];
    if (tid < H_N) {
        hbuf[0][tid >> 3][tid & 7] = (float)tid;
        hbuf[1][tid >> 3][tid & 7] = (float)tid;
    }
    __syncthreads();
    float acc = 0.f;
    for (int t = 0; t < T_N; t += 2) {
        {
            float4 hv0 = *(const float4*)&hbuf[0][p][0];
            float4 hv1 = *(const float4*)&hbuf[0][p][4];
            acc += hv0.x + hv1.w;
            if (p == 0) *(float4*)&hbuf[1][jg >> 1][(jg & 1) << 2] = hv0;
            asm volatile("s_waitcnt lgkmcnt(0)" ::: "memory");
            __builtin_amdgcn_s_barrier();
            asm volatile("" ::: "memory");
        }
        {
            float4 hv0 = *(const float4*)&hbuf[1][p][0];
            float4 hv1 = *(const float4*)&hbuf[1][p][4];
            acc += hv0.x + hv1.w;
            if (p == 0) *(float4*)&hbuf[0][jg >> 1][(jg & 1) << 2] = hv0;
            asm volatile("s_waitcnt lgkmcnt(0)" ::: "memory");
            __builtin_amdgcn_s_barrier();
            asm volatile("" ::: "memory");
        }
    }
    if (tid == 0) ws[128 + blockIdx.x] = acc;
}

// P3: the FULL scan step (DOT4 + DPP reduce + tanh + LDS handoff + barrier)
// with NO global load/store in the loop. scan - P3 isolates the global path.
__global__ __launch_bounds__(512, 1) void probe_novmem(
    const float* __restrict__ Whh, const float* __restrict__ bhh,
    const float* __restrict__ h0, float* ws)
{
    const int tid  = threadIdx.x;
    const int b    = blockIdx.x;
    const int lane = tid & 63;
    const int wv   = tid >> 6;
    const int p    = lane & 15;
    const int jg   = (lane >> 4) + 4 * wv;
    __shared__ float hbuf[2][16][12];

    float4 w4[4][2];
    #pragma unroll
    for (int j = 0; j < 4; ++j)
        #pragma unroll
        for (int c = 0; c < 2; ++c)
            w4[j][c] = *(const float4*)(Whh + (4 * jg + j) * H_N + 8 * p + 4 * c);

    const float4 bh4 = *(const float4*)(bhh + 4 * jg);
    const float4 xvf = *(const float4*)(h0 + ((b * H_N + 4 * jg) & (H_N * B_N - 4)));

    if (tid < H_N) hbuf[0][tid >> 3][tid & 7] = h0[b * H_N + tid];
    __syncthreads();

#define PSTEP(CUR) do {                                                       \
        float4 hv0 = *(const float4*)&hbuf[CUR][p][0];                        \
        float4 hv1 = *(const float4*)&hbuf[CUR][p][4];                        \
        float s0 = DOT4(w4[0][0], hv0) + DOT4(w4[0][1], hv1);                 \
        float s1 = DOT4(w4[1][0], hv0) + DOT4(w4[1][1], hv1);                 \
        float s2 = DOT4(w4[2][0], hv0) + DOT4(w4[2][1], hv1);                 \
        float s3 = DOT4(w4[3][0], hv0) + DOT4(w4[3][1], hv1);                 \
        s0 = ror_add(s0, ROR1); s1 = ror_add(s1, ROR1);                       \
        s2 = ror_add(s2, ROR1); s3 = ror_add(s3, ROR1);                       \
        s0 = ror_add(s0, ROR2); s1 = ror_add(s1, ROR2);                       \
        s2 = ror_add(s2, ROR2); s3 = ror_add(s3, ROR2);                       \
        s0 = ror_add(s0, ROR4); s1 = ror_add(s1, ROR4);                       \
        s2 = ror_add(s2, ROR4); s3 = ror_add(s3, ROR4);                       \
        s0 = ror_add(s0, ROR8); s1 = ror_add(s1, ROR8);                       \
        s2 = ror_add(s2, ROR8); s3 = ror_add(s3, ROR8);                       \
        float4 h4;                                                            \
        h4.x = tanh_pade(s0 + xvf.x + bh4.x);                                 \
        h4.y = tanh_pade(s1 + xvf.y + bh4.y);                                 \
        h4.z = tanh_pade(s2 + xvf.z + bh4.z);                                 \
        h4.w = tanh_pade(s3 + xvf.w + bh4.w);                                 \
        if (p == 0)                                                           \
            *(float4*)&hbuf[(CUR) ^ 1][jg >> 1][(jg & 1) << 2] = h4;          \
        asm volatile("s_waitcnt lgkmcnt(0)" ::: "memory");                    \
        __builtin_amdgcn_s_barrier();                                         \
        asm volatile("" ::: "memory");                                        \
    } while (0)

    for (int t = 0; t < T_N; t += 2) {
        PSTEP(0);
        PSTEP(1);
    }
#undef PSTEP

    float4 hv0 = *(const float4*)&hbuf[0][p][0];
    if (tid == 0) ws[192 + blockIdx.x] = hv0.x;
}

extern "C" void kernel_launch(void* const* d_in, const int* in_sizes, int n_in,
                              void* d_out, int out_size, void* d_ws, size_t ws_size,
                              hipStream_t stream) {
    const float* x   = (const float*)d_in[0];
    const float* h0  = (const float*)d_in[1];
    const float* Wih = (const float*)d_in[2];
    const float* Whh = (const float*)d_in[3];
    const float* bih = (const float*)d_in[4];
    const float* bhh = (const float*)d_in[5];
    float* out = (float*)d_out;
    float* ws  = (float*)d_ws;

    xproj_kernel<<<dim3((T_N * B_N) / 128), 256, 0, stream>>>(x, Wih, bih, out);
    scan_kernel<<<dim3(B_N), 512, 0, stream>>>(Whh, bhh, h0, out);

    // --- probes (timing decomposition; write only to d_ws) ---
    probe_clock  <<<dim3(B_N), 512, 0, stream>>>(ws);
    probe_barrier<<<dim3(B_N), 512, 0, stream>>>(ws);
    probe_lds    <<<dim3(B_N), 512, 0, stream>>>(ws);
    probe_novmem <<<dim3(B_N), 512, 0, stream>>>(Whh, bhh, h0, ws);
}